// Round 2
// 6312.556 us; speedup vs baseline: 1.1845x; 1.1845x over previous
//
#include <hip/hip_runtime.h>
#include <stdint.h>
#include <stddef.h>

typedef unsigned short u16;
typedef unsigned int u32;
typedef unsigned long long u64;
typedef __attribute__((ext_vector_type(8))) short short8;
typedef __attribute__((ext_vector_type(4))) float f32x4;
typedef __attribute__((ext_vector_type(2))) float f32x2;

#define B_    512
#define T_    1024
#define TM1_  1023
#define I_    32
#define E_    32
#define H_    256
#define GSZ   16          // blocks per group
#define NGRP  16          // number of groups
#define NTH   512         // threads per block (8 waves)
#define HBUF  (B_ * H_)   // elems per h state buffer (one parity), bf16 internal
#define OUTY_STRIDE (TM1_ * I_)            // 32736
#define OUTH_BASE ((size_t)B_ * TM1_ * I_) // 16760832
#define FLAG_STRIDE 16    // ints -> 64 B per flag line

__device__ __forceinline__ u16 f2bf(float f) {
  union { float f; unsigned int i; } c;
  c.f = f;
  unsigned int x = c.i;
  x += 0x7FFFu + ((x >> 16) & 1u);   // round-to-nearest-even
  return (u16)(x >> 16);
}
__device__ __forceinline__ short8 ld8bf(const float* p) {
  short8 rv;
#pragma unroll
  for (int j = 0; j < 8; ++j) rv[j] = (short)f2bf(p[j]);
  return rv;
}
__device__ __forceinline__ float sigm(float x) { return 1.f / (1.f + __expf(-x)); }
__device__ __forceinline__ float tanh_fast(float x) {
  x = fminf(15.f, fmaxf(-15.f, x));
  float e = __expf(2.f * x);
  return (e - 1.f) / (e + 1.f);
}
// volatile => sc0 sc1 on gfx950 (bypass L1 + per-XCD L2, served at the device
// coherence point) AND compiler no-reorder. This is the cross-XCD data path
// (proven by the round-0 kernel, which passed with this exact mechanism).
__device__ __forceinline__ u64 ldq_cp(const u64* p) { return *(volatile const u64*)p; }
__device__ __forceinline__ void stw_cp(u32* p, u32 v) { *(volatile u32*)p = v; }

// Persistent 2-layer GRU. Grid = 256 blocks (1/CU), 512 thr (8 waves).
// 16 groups x 16 blocks. Group g owns batch rows [g*32,g*32+32); block r owns
// h-dims [r*16,r*16+16) (48 gate rows) of both layers. Weights are
// register-resident bf16 MFMA B-fragments.
// Sync: per-block monotonic flags (consumer-pull). Producers store their h
// slice (volatile sc0sc1), __syncthreads (each wave drains vmcnt before
// s_barrier -> all stores at coherence point), tid0 bumps flag = t+1; they
// NEVER wait for peers. Consumers: wave0 polls the 16 peer flags (one lane
// per flag, system-scope atomic loads), one s_barrier releases the block.
// All h-independent GEMM parts run BEFORE the waits (acc regs live across).
// Hang-proof: any lane's poll timeout kills `alive` wave-wide via ballot ->
// all subsequent waits skipped -> kernel terminates in bounded time.
__global__ __launch_bounds__(NTH, 2)
void arrnn_persistent(
    const float* __restrict__ X, const float* __restrict__ ENC, const int* __restrict__ MASK,
    const float* __restrict__ wih0, const float* __restrict__ whh0,
    const float* __restrict__ bih0, const float* __restrict__ bhh0,
    const float* __restrict__ wih1, const float* __restrict__ whh1,
    const float* __restrict__ bih1, const float* __restrict__ bhh1,
    const float* __restrict__ wout, const float* __restrict__ bout,
    float* __restrict__ out, u16* __restrict__ h0g, u16* __restrict__ h1g,
    int* __restrict__ flags)
{
  __shared__ __align__(16) u16 sH0buf[32 * 264];   // 16896 B  h0 (A-operand k>=64)
  __shared__ __align__(16) u16 sH1buf[32 * 264];   // 16896 B  h1 (readout + phase B)
  __shared__ __align__(16) u16 sXE[32 * 72];       //  4608 B  [x|e] strip (k<64)
  __shared__ float sGates[4 * 32 * 20];            // 10240 B  padded rows (20)
  __shared__ float sH0loc[512];                    //  2048 B  fp32 carry, own slice
  __shared__ float sH1loc[512];
  __shared__ float sY[32 * 36];                    //  4608 B  padded rows (36)
  __shared__ int   sMk[32];                        //   128 B  per-row keep mask

  const int tid  = threadIdx.x;
  const int w    = tid >> 6;          // wave 0..7
  const int lane = tid & 63;
  const int quad = lane >> 4;         // 0..3
  const int l15  = lane & 15;
  const int g    = blockIdx.x >> 4;   // group 0..15
  const int r    = blockIdx.x & 15;   // slice 0..15
  const int hs   = r << 4;            // h-dim base of this block's slice
  const int row0 = g << 5;            // batch row base of group
  const int mt   = w & 1;             // M tile (16 rows each)
  const int gt   = w >> 1;            // 0=r, 1=z, 2=i_n, 3=h_n
  const int crow = tid >> 4;          // staging/combine: row 0..31
  const int cdim = tid & 15;          // staging/combine: dim 0..15

  short8 zero8 = {0, 0, 0, 0, 0, 0, 0, 0};

  // ---- preload weight B-fragments (fp32 -> bf16, once) ----
  const int grow = ((gt == 1) ? 256 : (gt >= 2 ? 512 : 0)) + hs + l15;

  short8 wfA[10];   // layer0: r/z K=320 over [wih0|whh0]; i_n K=64; h_n K=256
#pragma unroll
  for (int kk = 0; kk < 10; ++kk) {
    const int k = kk * 32 + quad * 8;
    const float* p;
    bool v;
    if (gt <= 1)      { v = true;     p = (k < 64) ? (wih0 + grow * 64 + k)
                                                   : (whh0 + grow * 256 + (k - 64)); }
    else if (gt == 2) { v = (kk < 2); p = wih0 + grow * 64 + (v ? k : 0); }
    else              { v = (kk < 8); p = whh0 + grow * 256 + (v ? k : 0); }
    wfA[kk] = v ? ld8bf(p) : zero8;
  }

  short8 wfB[16];   // layer1: r/z K=512 over [wih1|whh1]; i_n K=256; h_n K=256
#pragma unroll
  for (int kk = 0; kk < 16; ++kk) {
    const int k = kk * 32 + quad * 8;
    const float* p;
    bool v;
    if (gt <= 1)      { v = true;     p = (k < 256) ? (wih1 + grow * 256 + k)
                                                    : (whh1 + grow * 256 + (k - 256)); }
    else if (gt == 2) { v = (kk < 8); p = wih1 + grow * 256 + (v ? k : 0); }
    else              { v = (kk < 8); p = whh1 + grow * 256 + (v ? k : 0); }
    wfB[kk] = v ? ld8bf(p) : zero8;
  }

  const int yout = ((w >> 1) & 1) * 16 + l15;
  short8 wfY[8];
  if (w < 4) {
#pragma unroll
    for (int kk = 0; kk < 8; ++kk)
      wfY[kk] = ld8bf(wout + yout * 256 + kk * 32 + quad * 8);
  } else {
#pragma unroll
    for (int kk = 0; kk < 8; ++kk) wfY[kk] = zero8;
  }
  const float boutv = (w < 4) ? bout[yout] : 0.f;

  const int bd = hs + cdim;
  const float b0r  = bih0[bd]       + bhh0[bd];
  const float b0z  = bih0[256 + bd] + bhh0[256 + bd];
  const float b0ni = bih0[512 + bd];
  const float b0nh = bhh0[512 + bd];
  const float b1r  = bih1[bd]       + bhh1[bd];
  const float b1z  = bih1[256 + bd] + bhh1[256 + bd];
  const float b1ni = bih1[512 + bd];
  const float b1nh = bhh1[512 + bd];

  // zero LDS h bufs (t=0 reads them) + fp32 carries
  for (int i = tid; i < 4224; i += NTH) {
    ((u32*)sH0buf)[i] = 0u;
    ((u32*)sH1buf)[i] = 0u;
  }
  sH0loc[tid] = 0.f;
  sH1loc[tid] = 0.f;
  __syncthreads();

  const u64* h0q = (const u64*)h0g;
  const u64* h1q = (const u64*)h1g;
  u32* h0u = (u32*)h0g;
  u32* h1u = (u32*)h1g;

  int* fH0g  = flags + g * GSZ * FLAG_STRIDE;
  int* fH1g  = flags + NGRP * GSZ * FLAG_STRIDE + g * GSZ * FLAG_STRIDE;
  int* fH0own = fH0g + r * FLAG_STRIDE;
  int* fH1own = fH1g + r * FLAG_STRIDE;
  int alive = 1;

  // wave0 only: one lane per peer flag; exits when all 16 flags >= tgt.
  // Any lane timing out kills `alive` wave-wide -> every later wait skipped.
#define WAIT_FLAGS(basep, tgt)                                                   \
  do {                                                                           \
    int ok = 1;                                                                  \
    if (alive && lane < GSZ) {                                                   \
      const int* fp = (basep) + lane * FLAG_STRIDE;                              \
      int it = 0;                                                                \
      while (__hip_atomic_load(fp, __ATOMIC_RELAXED,                             \
                               __HIP_MEMORY_SCOPE_SYSTEM) < (tgt)) {             \
        __builtin_amdgcn_s_sleep(1);                                             \
        if (++it > (1 << 16)) { ok = 0; break; }                                 \
      }                                                                          \
    }                                                                            \
    if (__ballot(ok == 0) != 0ull) alive = 0;                                    \
  } while (0)

#define POST_FLAG(fp, val)                                                       \
  do {                                                                           \
    if (tid == 0) {                                                              \
      __builtin_amdgcn_s_waitcnt(0);                                             \
      __hip_atomic_store((fp), (val), __ATOMIC_RELAXED,                          \
                         __HIP_MEMORY_SCOPE_SYSTEM);                             \
    }                                                                            \
  } while (0)

  const int b = row0 + crow;          // this thread's staging batch row
  const int arow = mt * 16 + l15;     // GEMM A-row for this lane

  for (int t = 0; t < 1024; ++t) {
    const int par = t & 1;

    // ---- (a) prefetch x/e/mask + early sXE staging (e always, x if keep) ----
    int mk = 1;
    if (t < 1023) {
      f32x2 xld = *(const f32x2*)(X   + ((size_t)b * T_ + t)     * I_ + 2 * cdim);
      f32x2 eld = *(const f32x2*)(ENC + ((size_t)b * T_ + t + 1) * E_ + 2 * cdim);
      if (t > 0) mk = (MASK[b * T_ + t] != 0);
      u16* A = sXE + crow * 72;
      const int c2 = 2 * cdim;
      if (mk) { A[c2] = f2bf(xld.x); A[c2 + 1] = f2bf(xld.y); }
      A[32 + c2] = f2bf(eld.x); A[32 + c2 + 1] = f2bf(eld.y);
      if (cdim == 0) sMk[crow] = mk;
    }

    // ---- (b) phase A, h0(t-1)-part GEMM (sH0buf stable; acc lives in regs) ----
    f32x4 accA = {0.f, 0.f, 0.f, 0.f};
    if (t < 1023) {
      if (gt <= 1) {
        const u16* ah = sH0buf + arow * 264 + quad * 8;
#pragma unroll
        for (int kk = 2; kk < 10; ++kk) {
          short8 af = *(const short8*)(ah + (kk - 2) * 32);
          accA = __builtin_amdgcn_mfma_f32_16x16x32_bf16(af, wfA[kk], accA, 0, 0, 0);
        }
      } else if (gt == 3) {
        const u16* ah = sH0buf + arow * 264 + quad * 8;
#pragma unroll
        for (int kk = 0; kk < 8; ++kk) {
          short8 af = *(const short8*)(ah + kk * 32);
          accA = __builtin_amdgcn_mfma_f32_16x16x32_bf16(af, wfA[kk], accA, 0, 0, 0);
        }
      }
    }

    // ---- (d) wait h1(t-1) flags, stage sH1buf ----
    if (t > 0) {
      if (w == 0) WAIT_FLAGS(fH1g, t);
      __syncthreads();   // release
      const u64* hq = h1q + (size_t)par * 32768 + (size_t)b * 64 + cdim * 4;
      u64 q0 = ldq_cp(hq), q1 = ldq_cp(hq + 1), q2 = ldq_cp(hq + 2), q3 = ldq_cp(hq + 3);
      union { u64 q[2]; short8 s; } u0, u1;
      u0.q[0] = q0; u0.q[1] = q1; u1.q[0] = q2; u1.q[1] = q3;
      *(short8*)(sH1buf + crow * 264 + cdim * 16)     = u0.s;
      *(short8*)(sH1buf + crow * 264 + cdim * 16 + 8) = u1.s;
    }
    __syncthreads();

    // ---- (f) readout y(t-1); feed masked-x columns of sXE straight from acc ----
    if (t > 0 && w < 4) {
      const u16* ap = sH1buf + (mt * 16 + l15) * 264 + quad * 8;
      f32x4 acc = {0.f, 0.f, 0.f, 0.f};
#pragma unroll
      for (int kk = 0; kk < 8; ++kk) {
        short8 af = *(const short8*)(ap + kk * 32);
        acc = __builtin_amdgcn_mfma_f32_16x16x32_bf16(af, wfY[kk], acc, 0, 0, 0);
      }
#pragma unroll
      for (int rg = 0; rg < 4; ++rg) {
        const int row = mt * 16 + quad * 4 + rg;
        const float yv = acc[rg] + boutv;
        sY[row * 36 + yout] = yv;
        if (t < 1023 && !sMk[row]) sXE[row * 72 + yout] = f2bf(yv);
      }
    }
    __syncthreads();

    if (t > 0 && tid < 64) {   // this block's 2-row share of output
      const int lr = r * 2 + (tid >> 5);
      const int lc = tid & 31;
      out[(size_t)(row0 + lr) * OUTY_STRIDE + (size_t)(t - 1) * I_ + lc] =
          sY[lr * 36 + lc];
    }
    if (t == 1023) break;

    // ---- (h) phase A, xe-part GEMM + publish gates ----
    if (gt <= 2) {
      const u16* axe = sXE + arow * 72 + quad * 8;
#pragma unroll
      for (int kk = 0; kk < 2; ++kk) {
        short8 af = *(const short8*)(axe + kk * 32);
        accA = __builtin_amdgcn_mfma_f32_16x16x32_bf16(af, wfA[kk], accA, 0, 0, 0);
      }
    }
#pragma unroll
    for (int rg = 0; rg < 4; ++rg)
      sGates[(gt * 32 + mt * 16 + quad * 4 + rg) * 20 + l15] = accA[rg];
    __syncthreads();

    // ---- (j) combine -> h0(t); volatile (sc0sc1) packed store ----
    {
      const float gr = sGates[(0 * 32 + crow) * 20 + cdim] + b0r;
      const float gz = sGates[(1 * 32 + crow) * 20 + cdim] + b0z;
      const float gi = sGates[(2 * 32 + crow) * 20 + cdim] + b0ni;
      const float gh = sGates[(3 * 32 + crow) * 20 + cdim] + b0nh;
      const float rr = sigm(gr);
      const float zz = sigm(gz);
      const float nn = tanh_fast(gi + rr * gh);
      const float hv = (1.f - zz) * nn + zz * sH0loc[tid];
      sH0loc[tid] = hv;
      const float hp = __shfl_xor(hv, 1, 64);
      if (!(tid & 1)) {
        u32 pk = (u32)f2bf(hv) | ((u32)f2bf(hp) << 16);
        stw_cp(h0u + (size_t)(par ^ 1) * 65536 + (size_t)b * 128 + ((hs + cdim) >> 1), pk);
      }
    }
    __syncthreads();                    // all waves' h0 stores drained pre-barrier
    POST_FLAG(fH0own, t + 1);

    // ---- phase B, h1(t-1)-part GEMM (overlaps the h0 hop; acc in regs) ----
    f32x4 accB = {0.f, 0.f, 0.f, 0.f};
    if (gt <= 1) {
      const u16* a1 = sH1buf + arow * 264 + quad * 8;
#pragma unroll
      for (int kk = 0; kk < 8; ++kk) {
        short8 af = *(const short8*)(a1 + kk * 32);
        accB = __builtin_amdgcn_mfma_f32_16x16x32_bf16(af, wfB[kk + 8], accB, 0, 0, 0);
      }
    } else if (gt == 3) {
      const u16* a1 = sH1buf + arow * 264 + quad * 8;
#pragma unroll
      for (int kk = 0; kk < 8; ++kk) {
        short8 af = *(const short8*)(a1 + kk * 32);
        accB = __builtin_amdgcn_mfma_f32_16x16x32_bf16(af, wfB[kk], accB, 0, 0, 0);
      }
    }

    // ---- wait h0(t) flags, stage sH0buf ----
    if (w == 0) WAIT_FLAGS(fH0g, t + 1);
    __syncthreads();   // release
    {
      const u64* hq = h0q + (size_t)(par ^ 1) * 32768 + (size_t)b * 64 + cdim * 4;
      u64 q0 = ldq_cp(hq), q1 = ldq_cp(hq + 1), q2 = ldq_cp(hq + 2), q3 = ldq_cp(hq + 3);
      union { u64 q[2]; short8 s; } u0, u1;
      u0.q[0] = q0; u0.q[1] = q1; u1.q[0] = q2; u1.q[1] = q3;
      *(short8*)(sH0buf + crow * 264 + cdim * 16)     = u0.s;
      *(short8*)(sH0buf + crow * 264 + cdim * 16 + 8) = u1.s;
    }
    __syncthreads();

    // ---- phase B, h0(t)-part GEMM + publish gates ----
    if (gt <= 2) {
      const u16* a0 = sH0buf + arow * 264 + quad * 8;
#pragma unroll
      for (int kk = 0; kk < 8; ++kk) {
        short8 af = *(const short8*)(a0 + kk * 32);
        accB = __builtin_amdgcn_mfma_f32_16x16x32_bf16(af, wfB[kk], accB, 0, 0, 0);
      }
    }
#pragma unroll
    for (int rg = 0; rg < 4; ++rg)
      sGates[(gt * 32 + mt * 16 + quad * 4 + rg) * 20 + l15] = accB[rg];
    __syncthreads();

    // ---- combine -> h1(t); volatile (sc0sc1) packed store ----
    {
      const float gr = sGates[(0 * 32 + crow) * 20 + cdim] + b1r;
      const float gz = sGates[(1 * 32 + crow) * 20 + cdim] + b1z;
      const float gi = sGates[(2 * 32 + crow) * 20 + cdim] + b1ni;
      const float gh = sGates[(3 * 32 + crow) * 20 + cdim] + b1nh;
      const float rr = sigm(gr);
      const float zz = sigm(gz);
      const float nn = tanh_fast(gi + rr * gh);
      const float hv = (1.f - zz) * nn + zz * sH1loc[tid];
      sH1loc[tid] = hv;
      const float hp = __shfl_xor(hv, 1, 64);
      if (!(tid & 1)) {
        u32 pk = (u32)f2bf(hv) | ((u32)f2bf(hp) << 16);
        stw_cp(h1u + (size_t)(par ^ 1) * 65536 + (size_t)b * 128 + ((hs + cdim) >> 1), pk);
      }
    }
    __syncthreads();                    // all waves' h1 stores drained pre-barrier
    POST_FLAG(fH1own, t + 1);
  }

  // final hidden state h1(T-2): own fp32 slice
  out[OUTH_BASE + (size_t)b * H_ + hs + cdim] = sH1loc[tid];
#undef WAIT_FLAGS
#undef POST_FLAG
}

extern "C" void kernel_launch(void* const* d_in, const int* in_sizes, int n_in,
                              void* d_out, int out_size, void* d_ws, size_t ws_size,
                              hipStream_t stream) {
  (void)in_sizes; (void)n_in; (void)out_size; (void)ws_size;
  const float* X    = (const float*)d_in[0];
  const float* ENC  = (const float*)d_in[1];
  const int*   MASK = (const int*)d_in[2];
  const float* wih0 = (const float*)d_in[3];
  const float* whh0 = (const float*)d_in[4];
  const float* bih0 = (const float*)d_in[5];
  const float* bhh0 = (const float*)d_in[6];
  const float* wih1 = (const float*)d_in[7];
  const float* whh1 = (const float*)d_in[8];
  const float* bih1 = (const float*)d_in[9];
  const float* bhh1 = (const float*)d_in[10];
  const float* wout = (const float*)d_in[11];
  const float* bout = (const float*)d_in[12];
  float* out = (float*)d_out;

  char* ws = (char*)d_ws;
  u16* h0g = (u16*)ws;                                  // 2 x 512x256 bf16
  u16* h1g = (u16*)(ws + 2 * (size_t)HBUF * 2);         // 2 x 512x256 bf16
  int* flags = (int*)(ws + 4 * (size_t)HBUF * 2);       // 2 phases x 256 lines x 64B

  hipMemsetAsync(flags, 0, 2 * NGRP * GSZ * FLAG_STRIDE * sizeof(int), stream);
  arrnn_persistent<<<dim3(NGRP * GSZ), dim3(NTH), 0, stream>>>(
      X, ENC, MASK, wih0, whh0, bih0, bhh0, wih1, whh1, bih1, bhh1,
      wout, bout, out, h0g, h1g, flags);
}

// Round 4
// 5383.357 us; speedup vs baseline: 1.3890x; 1.1726x over previous
//
#include <hip/hip_runtime.h>
#include <stdint.h>
#include <stddef.h>

typedef unsigned short u16;
typedef unsigned int u32;
typedef unsigned long long u64;
typedef __attribute__((ext_vector_type(8))) short short8;
typedef __attribute__((ext_vector_type(4))) float f32x4;
typedef __attribute__((ext_vector_type(2))) float f32x2;

#define B_    512
#define T_    1024
#define TM1_  1023
#define I_    32
#define E_    32
#define H_    256
#define GSZ   8           // blocks per group
#define NGRP  32          // number of groups
#define NTH   512         // threads per block (8 waves)
#define MBOX_PAR (B_ * H_)                 // u32 words per mailbox parity (131072)
#define OUTY_STRIDE (TM1_ * I_)            // 32736
#define OUTH_BASE ((size_t)B_ * TM1_ * I_) // 16760832

__device__ __forceinline__ u16 f2bf(float f) {
  union { float f; unsigned int i; } c;
  c.f = f;
  unsigned int x = c.i;
  x += 0x7FFFu + ((x >> 16) & 1u);   // round-to-nearest-even
  return (u16)(x >> 16);
}
__device__ __forceinline__ short8 ld8bf(const float* p) {
  short8 rv;
#pragma unroll
  for (int j = 0; j < 8; ++j) rv[j] = (short)f2bf(p[j]);
  return rv;
}
__device__ __forceinline__ float sigm(float x) { return 1.f / (1.f + __expf(-x)); }
__device__ __forceinline__ float tanh_fast(float x) {
  x = fminf(15.f, fmaxf(-15.f, x));
  float e = __expf(2.f * x);
  return (e - 1.f) / (e + 1.f);
}
// volatile => sc0 sc1 on gfx950 (bypass L1 + per-XCD L2, served at the device
// coherence point) AND compiler no-reorder. Cross-XCD data path (proven r0/r2).
__device__ __forceinline__ u64 ldq_cp(const u64* p) { return *(volatile const u64*)p; }
__device__ __forceinline__ void stw_cp(u32* p, u32 v) { *(volatile u32*)p = v; }

// Persistent 2-layer GRU. Grid = 256 blocks (1/CU), 512 thr (8 waves).
// 32 groups x 8 blocks. Group g owns batch rows [g*16,g*16+16); block r owns
// h-dims [r*32,r*32+32) (96 gate rows) of both layers. Weights are
// register-resident bf16 MFMA B-fragments (8 waves = 4 gate types x 2 N-tiles).
//
// Sync: TAGGED MAILBOXES. Every exchanged h value is one u32:
//   word = bf16(h) << 16 | (step+1).
// Producer: one plain volatile store per value, no flag, no drain-wait, no
// trailing barrier (each word self-validates; 32-bit stores are atomic).
// Consumer: each thread polls its own 8 words (4 u64 loads in flight);
// when all 8 tags match, the SAME load already delivered the payload ->
// detection = data arrival = ONE round trip per hop (was ~3-4 RTs via flags).
// Parity double-buffer bounds producer lead, so a parity slot for step t is
// never overwritten (step t+2) before all peers consumed step t.
// Mailboxes are memset per launch so stale tags from a prior run can't alias.
// Hang-proof: per-thread bounded spin; first timeout kills `alive` -> all
// later spins skip -> kernel terminates in bounded time (wrong result, no hang).
//
// r3 bug fixed here: combine read gate tiles ((0|2|4|6)<<1) — i.e. tiles
// 0/4/8/12, where 8/12 are OOB of sGates. Publisher writes tile (gt<<1)|nt,
// gt in {0..3}; combine must read tiles ((0..3)<<1)|ntc.
__global__ __launch_bounds__(NTH, 2)
void arrnn_persistent(
    const float* __restrict__ X, const float* __restrict__ ENC, const int* __restrict__ MASK,
    const float* __restrict__ wih0, const float* __restrict__ whh0,
    const float* __restrict__ bih0, const float* __restrict__ bhh0,
    const float* __restrict__ wih1, const float* __restrict__ whh1,
    const float* __restrict__ bih1, const float* __restrict__ bhh1,
    const float* __restrict__ wout, const float* __restrict__ bout,
    float* __restrict__ out, u32* __restrict__ h0m, u32* __restrict__ h1m)
{
  __shared__ __align__(16) u16 sH0buf[16 * 264];   // 8448 B  h0 (phase A k>=64, phase B)
  __shared__ __align__(16) u16 sH1buf[16 * 264];   // 8448 B  h1 (readout + phase B)
  __shared__ __align__(16) u16 sXE[16 * 72];       // 2304 B  [x|e] strip (k<64)
  __shared__ float sGates[8 * 16 * 20];            // 10240 B (gt,nt) tiles, padded 20
  __shared__ float sH0loc[512];                    // 2048 B  fp32 carry, own slice
  __shared__ float sH1loc[512];
  __shared__ float sY[16 * 36];                    // 2304 B
  __shared__ int   sMk[16];

  const int tid  = threadIdx.x;
  const int w    = tid >> 6;          // wave 0..7
  const int lane = tid & 63;
  const int quad = lane >> 4;         // 0..3
  const int l15  = lane & 15;
  const int g    = blockIdx.x >> 3;   // group 0..31
  const int r    = blockIdx.x & 7;    // slice 0..7
  const int hs   = r << 5;            // h-dim base of this block's 32-dim slice
  const int row0 = g << 4;            // batch row base of group (16 rows)
  const int gt   = w >> 1;            // 0=r, 1=z, 2=i_n, 3=h_n
  const int nt   = w & 1;             // N-tile within the 32-dim slice
  const int crow = tid >> 5;          // staging/combine: row 0..15
  const int c32  = tid & 31;          // staging/combine: dim 0..31

  short8 zero8 = {0, 0, 0, 0, 0, 0, 0, 0};

  // ---- preload weight B-fragments (fp32 -> bf16, once) ----
  // B-frag: lane holds B[k=quad*8+j][n]; n = this wave's gate row.
  const int gateofs = (gt == 1) ? 256 : (gt >= 2 ? 512 : 0);
  const int grow = gateofs + hs + (nt << 4) + l15;

  short8 wfA[10];   // layer0: r/z K=320 over [wih0|whh0]; i_n K=64; h_n K=256
#pragma unroll
  for (int kk = 0; kk < 10; ++kk) {
    const int k = kk * 32 + quad * 8;
    const float* p;
    bool v;
    if (gt <= 1)      { v = true;     p = (k < 64) ? (wih0 + grow * 64 + k)
                                                   : (whh0 + grow * 256 + (k - 64)); }
    else if (gt == 2) { v = (kk < 2); p = wih0 + grow * 64 + (v ? k : 0); }
    else              { v = (kk < 8); p = whh0 + grow * 256 + (v ? k : 0); }
    wfA[kk] = v ? ld8bf(p) : zero8;
  }

  short8 wfB[16];   // layer1: r/z K=512 over [wih1|whh1]; i_n K=256; h_n K=256
#pragma unroll
  for (int kk = 0; kk < 16; ++kk) {
    const int k = kk * 32 + quad * 8;
    const float* p;
    bool v;
    if (gt <= 1)      { v = true;     p = (k < 256) ? (wih1 + grow * 256 + k)
                                                    : (whh1 + grow * 256 + (k - 256)); }
    else if (gt == 2) { v = (kk < 8); p = wih1 + grow * 256 + (v ? k : 0); }
    else              { v = (kk < 8); p = whh1 + grow * 256 + (v ? k : 0); }
    wfB[kk] = v ? ld8bf(p) : zero8;
  }

  // readout: waves 0,1 handle N-tile w (16 out cols), full K=256
  const int ycol = (w << 4) + l15;    // valid for w<2
  short8 wfY[8];
  if (w < 2) {
#pragma unroll
    for (int kk = 0; kk < 8; ++kk)
      wfY[kk] = ld8bf(wout + ycol * 256 + kk * 32 + quad * 8);
  } else {
#pragma unroll
    for (int kk = 0; kk < 8; ++kk) wfY[kk] = zero8;
  }
  const float boutv = (w < 2) ? bout[ycol] : 0.f;

  const int bd = hs + c32;
  const float b0r  = bih0[bd]       + bhh0[bd];
  const float b0z  = bih0[256 + bd] + bhh0[256 + bd];
  const float b0ni = bih0[512 + bd];
  const float b0nh = bhh0[512 + bd];
  const float b1r  = bih1[bd]       + bhh1[bd];
  const float b1z  = bih1[256 + bd] + bhh1[256 + bd];
  const float b1ni = bih1[512 + bd];
  const float b1nh = bhh1[512 + bd];

  // zero LDS h bufs (t=0 reads them) + fp32 carries
  for (int i = tid; i < 2112; i += NTH) {
    ((u32*)sH0buf)[i] = 0u;
    ((u32*)sH1buf)[i] = 0u;
  }
  sH0loc[tid] = 0.f;
  sH1loc[tid] = 0.f;
  __syncthreads();

  int alive = 1;
  const int b = row0 + crow;          // this thread's staging/combine batch row

  // Poll own 8 words (tag == exp in every word), then unpack bf16 payload.
#define SPIN_STAGE(mboxu32, expTag, dstbuf)                                      \
  do {                                                                           \
    const u64* qp = (const u64*)(mboxu32) + (size_t)b * 128 + c32 * 4;           \
    const u64 tagp = (u64)(u32)(expTag) | ((u64)(u32)(expTag) << 32);            \
    u64 q0, q1, q2, q3;                                                          \
    int it = 0;                                                                  \
    for (;;) {                                                                   \
      q0 = ldq_cp(qp); q1 = ldq_cp(qp + 1); q2 = ldq_cp(qp + 2); q3 = ldq_cp(qp + 3); \
      u64 dd = ((q0 ^ tagp) | (q1 ^ tagp) | (q2 ^ tagp) | (q3 ^ tagp))           \
               & 0x0000FFFF0000FFFFull;                                          \
      if (dd == 0 || !alive) break;                                              \
      if (++it > (1 << 16)) { alive = 0; break; }                                \
    }                                                                            \
    short8 sv;                                                                   \
    sv[0] = (short)(u16)(q0 >> 16); sv[1] = (short)(u16)(q0 >> 48);              \
    sv[2] = (short)(u16)(q1 >> 16); sv[3] = (short)(u16)(q1 >> 48);              \
    sv[4] = (short)(u16)(q2 >> 16); sv[5] = (short)(u16)(q2 >> 48);              \
    sv[6] = (short)(u16)(q3 >> 16); sv[7] = (short)(u16)(q3 >> 48);              \
    *(short8*)((dstbuf) + crow * 264 + c32 * 8) = sv;                            \
  } while (0)

  for (int t = 0; t < 1024; ++t) {
    const int par = t & 1;

    // ---- (a) stage x/e/mask into sXE (masked-x cols filled later from y) ----
    int mk = 1;
    if (t < 1023) {
      if (c32 < 16) {
        if (t > 0) mk = (MASK[b * T_ + t] != 0);
        f32x2 xld = *(const f32x2*)(X + ((size_t)b * T_ + t) * I_ + 2 * c32);
        if (mk) { sXE[crow * 72 + 2 * c32] = f2bf(xld.x);
                  sXE[crow * 72 + 2 * c32 + 1] = f2bf(xld.y); }
        if (c32 == 0) sMk[crow] = mk;
      } else {
        const int c2 = c32 - 16;
        f32x2 eld = *(const f32x2*)(ENC + ((size_t)b * T_ + t + 1) * E_ + 2 * c2);
        sXE[crow * 72 + 32 + 2 * c2] = f2bf(eld.x);
        sXE[crow * 72 + 32 + 2 * c2 + 1] = f2bf(eld.y);
      }
    }

    // ---- (1) phase A, h0(t-1)-part GEMM (sH0buf stable; acc lives in regs) ----
    f32x4 accA = {0.f, 0.f, 0.f, 0.f};
    if (t < 1023) {
      const u16* ah = sH0buf + l15 * 264 + quad * 8;
      if (gt <= 1) {
#pragma unroll
        for (int kk = 2; kk < 10; ++kk)
          accA = __builtin_amdgcn_mfma_f32_16x16x32_bf16(
              *(const short8*)(ah + (kk - 2) * 32), wfA[kk], accA, 0, 0, 0);
      } else if (gt == 3) {
#pragma unroll
        for (int kk = 0; kk < 8; ++kk)
          accA = __builtin_amdgcn_mfma_f32_16x16x32_bf16(
              *(const short8*)(ah + kk * 32), wfA[kk], accA, 0, 0, 0);
      }
    }

    // ---- (2) poll h1(t-1) mailbox (tag t), stage sH1buf ----
    if (t > 0) SPIN_STAGE(h1m + (size_t)par * MBOX_PAR, t, sH1buf);
    __syncthreads();

    // ---- (3) readout y(t-1): waves 0,1; write sY (+bias) ----
    if (t > 0 && w < 2) {
      const u16* ap = sH1buf + l15 * 264 + quad * 8;
      f32x4 acc = {0.f, 0.f, 0.f, 0.f};
#pragma unroll
      for (int kk = 0; kk < 8; ++kk)
        acc = __builtin_amdgcn_mfma_f32_16x16x32_bf16(
            *(const short8*)(ap + kk * 32), wfY[kk], acc, 0, 0, 0);
#pragma unroll
      for (int rg = 0; rg < 4; ++rg)
        sY[(quad * 4 + rg) * 36 + ycol] = acc[rg] + boutv;
    }
    __syncthreads();

    // ---- (4) write out y(t-1); feed masked-x columns of sXE from y ----
    if (t > 0) {
      if (tid < 64) {
        const int lr = (r << 1) + (tid >> 5);
        const int lc = tid & 31;
        out[(size_t)(row0 + lr) * OUTY_STRIDE + (size_t)(t - 1) * I_ + lc] =
            sY[lr * 36 + lc];
      }
      if (t < 1023 && !sMk[crow])
        sXE[crow * 72 + c32] = f2bf(sY[crow * 36 + c32]);
    }
    if (t == 1023) break;
    __syncthreads();

    // ---- (5) phase A, xe-part GEMM + publish gates ----
    if (gt <= 2) {
      const u16* axe = sXE + l15 * 72 + quad * 8;
#pragma unroll
      for (int kk = 0; kk < 2; ++kk)
        accA = __builtin_amdgcn_mfma_f32_16x16x32_bf16(
            *(const short8*)(axe + kk * 32), wfA[kk], accA, 0, 0, 0);
    }
#pragma unroll
    for (int rg = 0; rg < 4; ++rg)
      sGates[((gt << 1) | nt) * 320 + (quad * 4 + rg) * 20 + l15] = accA[rg];
    __syncthreads();

    // ---- (6) combine -> h0(t); ONE tagged store per thread, no barrier ----
    {
      const int ntc = c32 >> 4, cc = c32 & 15;
      const float gr = sGates[((0 << 1) | ntc) * 320 + crow * 20 + cc] + b0r;
      const float gz = sGates[((1 << 1) | ntc) * 320 + crow * 20 + cc] + b0z;
      const float gi = sGates[((2 << 1) | ntc) * 320 + crow * 20 + cc] + b0ni;
      const float gh = sGates[((3 << 1) | ntc) * 320 + crow * 20 + cc] + b0nh;
      const float rr = sigm(gr);
      const float zz = sigm(gz);
      const float nn = tanh_fast(gi + rr * gh);
      const float hv = (1.f - zz) * nn + zz * sH0loc[tid];
      sH0loc[tid] = hv;
      stw_cp(h0m + (size_t)(par ^ 1) * MBOX_PAR + (size_t)b * H_ + hs + c32,
             ((u32)f2bf(hv) << 16) | (u32)(t + 1));
    }

    // ---- (7) phase B, h1(t-1)-part GEMM (overlaps the h0 hop) ----
    f32x4 accB = {0.f, 0.f, 0.f, 0.f};
    {
      const u16* a1 = sH1buf + l15 * 264 + quad * 8;
      if (gt <= 1) {
#pragma unroll
        for (int kk = 0; kk < 8; ++kk)
          accB = __builtin_amdgcn_mfma_f32_16x16x32_bf16(
              *(const short8*)(a1 + kk * 32), wfB[kk + 8], accB, 0, 0, 0);
      } else if (gt == 3) {
#pragma unroll
        for (int kk = 0; kk < 8; ++kk)
          accB = __builtin_amdgcn_mfma_f32_16x16x32_bf16(
              *(const short8*)(a1 + kk * 32), wfB[kk], accB, 0, 0, 0);
      }
    }

    // ---- (8) poll h0(t) mailbox (tag t+1), stage sH0buf ----
    SPIN_STAGE(h0m + (size_t)(par ^ 1) * MBOX_PAR, t + 1, sH0buf);
    __syncthreads();

    // ---- (9) phase B, h0(t)-part GEMM + publish gates ----
    if (gt <= 2) {
      const u16* a0 = sH0buf + l15 * 264 + quad * 8;
#pragma unroll
      for (int kk = 0; kk < 8; ++kk)
        accB = __builtin_amdgcn_mfma_f32_16x16x32_bf16(
            *(const short8*)(a0 + kk * 32), wfB[kk], accB, 0, 0, 0);
    }
#pragma unroll
    for (int rg = 0; rg < 4; ++rg)
      sGates[((gt << 1) | nt) * 320 + (quad * 4 + rg) * 20 + l15] = accB[rg];
    __syncthreads();

    // ---- (10) combine -> h1(t); ONE tagged store per thread, no barrier ----
    {
      const int ntc = c32 >> 4, cc = c32 & 15;
      const float gr = sGates[((0 << 1) | ntc) * 320 + crow * 20 + cc] + b1r;
      const float gz = sGates[((1 << 1) | ntc) * 320 + crow * 20 + cc] + b1z;
      const float gi = sGates[((2 << 1) | ntc) * 320 + crow * 20 + cc] + b1ni;
      const float gh = sGates[((3 << 1) | ntc) * 320 + crow * 20 + cc] + b1nh;
      const float rr = sigm(gr);
      const float zz = sigm(gz);
      const float nn = tanh_fast(gi + rr * gh);
      const float hv = (1.f - zz) * nn + zz * sH1loc[tid];
      sH1loc[tid] = hv;
      stw_cp(h1m + (size_t)(par ^ 1) * MBOX_PAR + (size_t)b * H_ + hs + c32,
             ((u32)f2bf(hv) << 16) | (u32)(t + 1));
    }
  }

  // final hidden state h1(T-2): own fp32 slice
  out[OUTH_BASE + (size_t)b * H_ + hs + c32] = sH1loc[tid];
#undef SPIN_STAGE
}

extern "C" void kernel_launch(void* const* d_in, const int* in_sizes, int n_in,
                              void* d_out, int out_size, void* d_ws, size_t ws_size,
                              hipStream_t stream) {
  (void)in_sizes; (void)n_in; (void)out_size; (void)ws_size;
  const float* X    = (const float*)d_in[0];
  const float* ENC  = (const float*)d_in[1];
  const int*   MASK = (const int*)d_in[2];
  const float* wih0 = (const float*)d_in[3];
  const float* whh0 = (const float*)d_in[4];
  const float* bih0 = (const float*)d_in[5];
  const float* bhh0 = (const float*)d_in[6];
  const float* wih1 = (const float*)d_in[7];
  const float* whh1 = (const float*)d_in[8];
  const float* bih1 = (const float*)d_in[9];
  const float* bhh1 = (const float*)d_in[10];
  const float* wout = (const float*)d_in[11];
  const float* bout = (const float*)d_in[12];
  float* out = (float*)d_out;

  u32* h0m = (u32*)d_ws;                 // 2 parities x 512x256 tagged u32 (1 MB)
  u32* h1m = h0m + 2 * (size_t)MBOX_PAR; // 2 parities x 512x256 tagged u32 (1 MB)

  // Clear tags so a prior launch's tags can't alias this run's expected tags.
  hipMemsetAsync(h0m, 0, 4 * (size_t)MBOX_PAR * sizeof(u32), stream);
  arrnn_persistent<<<dim3(NGRP * GSZ), dim3(NTH), 0, stream>>>(
      X, ENC, MASK, wih0, whh0, bih0, bhh0, wih1, whh1, bih1, bhh1,
      wout, bout, out, h0m, h1m);
}